// Round 6
// baseline (39.322 us; speedup 1.0000x reference)
//
#include <hip/hip_runtime.h>

namespace {

constexpr int B = 16, H = 512, W = 512, N = 256;
constexpr int HWc = H * W;              // 262144
constexpr int NBLK = 1024;              // grid size (power of 2 for arrival mask)
constexpr int NTHR = 256;
constexpr int TEXT_SLOTS = 32;          // text partial-sum slots (spread atomics)
// log2-domain clamp: max(ln(p), -100) == ln2 * max(log2(p), -100/ln2)
constexpr float LOG2_CLAMP = -144.26950408889634f;
constexpr float LN2 = 0.69314718055994531f;

// All cross-block state lives in module __device__ globals: zero-initialized
// at module load (the harness poisons d_ws/d_out, never module globals).
// Invariant: every call leaves them at zero — the finalize block drains each
// slot with atomicExch(slot, 0). All accesses are device-scope atomic RMWs,
// which execute at the coherent point (LLC) — immune to the per-XCD L2
// non-coherence that broke the previous (load-based) design.
__device__ float    g_slot[TEXT_SLOTS + 3 * 16];  // [0,32) text | [32,48) l1 | [48,64) conf | [64,80) valid
__device__ unsigned g_cnt;                        // monotonic arrival counter

constexpr int SL_L1 = TEXT_SLOTS, SL_CL = TEXT_SLOTS + 16, SL_VF = TEXT_SLOTS + 32;

// BCE in log2 domain (== bce/ln2). Native v_log_f32; log2(0) = -inf -> clamped.
__device__ __forceinline__ float bce2(float p, float t) {
    float m1 = fmaxf(__log2f(p), LOG2_CLAMP);
    float m2 = fmaxf(__log2f(1.0f - p), LOG2_CLAMP);
    return fmaf(t, m2 - m1, -m2);          // -(t*m1 + (1-t)*m2)
}

__device__ __forceinline__ float smooth_l1(float pred, float tgt) {
    float d = fabsf(pred - tgt);
    return d < 1.0f ? 0.5f * d * d : d - 0.5f;
}

// Full-block (256-thread) sum; result valid on thread 0. Reusable (guarded).
__device__ __forceinline__ float block_reduce_sum(float v) {
    __shared__ float smem[4];
    for (int off = 32; off > 0; off >>= 1)
        v += __shfl_down(v, off, 64);
    int lane = threadIdx.x & 63, wid = threadIdx.x >> 6;
    __syncthreads();                       // guard smem reuse across calls
    if (lane == 0) smem[wid] = v;
    __syncthreads();
    if (threadIdx.x == 0) v = smem[0] + smem[1] + smem[2] + smem[3];
    return v;
}

// Single fused kernel: text BCE + box losses + last-block finalize.
__global__ __launch_bounds__(NTHR) void fused_kernel(
        const float4* __restrict__ p4,
        const float4* __restrict__ t4,
        const float*  __restrict__ conf_pred,
        const float*  __restrict__ bbox_pred,
        const float*  __restrict__ box_conf,
        const int*    __restrict__ box_xyxy,
        const int*    __restrict__ box_mask,
        float* __restrict__ out) {
    // ---- text-map BCE: 1,048,576 float4s, exactly 4 per thread ----
    int idx = blockIdx.x * NTHR + threadIdx.x;
    float acc = 0.0f;
    #pragma unroll
    for (int it = 0; it < 4; ++it) {
        int i = idx + it * (NBLK * NTHR);
        float4 p = p4[i];
        float4 t = t4[i];
        acc += bce2(p.x, t.x) + bce2(p.y, t.y) + bce2(p.z, t.z) + bce2(p.w, t.w);
    }
    float s = block_reduce_sum(acc);
    if (threadIdx.x == 0)
        atomicAdd(&g_slot[blockIdx.x & (TEXT_SLOTS - 1)], s);   // LLC RMW

    // ---- blocks 0..15: one batch of 256 boxes each (thread n = box n) ----
    if (blockIdx.x < B) {
        int b = blockIdx.x, n = threadIdx.x;
        int bi = b * N + n;
        int4 xy = reinterpret_cast<const int4*>(box_xyxy)[bi];  // x1,y1,x2,y2 in [0,512)
        int cx = (xy.x + xy.z) >> 1;       // nonneg -> >>1 == floor div 2
        int cy = (xy.y + xy.w) >> 1;
        bool valid = (box_mask[bi] != 0) && cx >= 0 && cx < W && cy >= 0 && cy < H;
        int cxc = min(max(cx, 0), W - 1);
        int cyc = min(max(cy, 0), H - 1);

        int base = ((b * 4) * H + cyc) * W + cxc;   // bbox_pred[b, 0, cy, cx]
        float l1 = 0.25f * (smooth_l1(bbox_pred[base          ], (float)xy.x * (1.0f / W)) +
                            smooth_l1(bbox_pred[base +     HWc], (float)xy.y * (1.0f / H)) +
                            smooth_l1(bbox_pred[base + 2 * HWc], (float)xy.z * (1.0f / W)) +
                            smooth_l1(bbox_pred[base + 3 * HWc], (float)xy.w * (1.0f / H)));
        float cl = bce2(conf_pred[(b * H + cyc) * W + cxc], box_conf[bi]);  // log2 dom

        float vf = valid ? 1.0f : 0.0f;
        float s1 = block_reduce_sum(l1 * vf);
        float s2 = block_reduce_sum(cl * vf);
        float s3 = block_reduce_sum(vf);
        if (threadIdx.x == 0) {
            atomicAdd(&g_slot[SL_L1 + b], s1);
            atomicAdd(&g_slot[SL_CL + b], s2);     // log2 domain; ×ln2 at end
            atomicAdd(&g_slot[SL_VF + b], s3);
        }
    }

    // ---- arrival: monotonic counter; per call olds are K..K+1023 for any K,
    //      so (old & 1023) == 1023 fires exactly once per call. ----
    __shared__ bool is_last;
    if (threadIdx.x == 0) {
        __threadfence();                   // drain this block's slot RMWs first
        unsigned old = atomicAdd(&g_cnt, 1u);
        is_last = ((old & (unsigned)(NBLK - 1)) == (unsigned)(NBLK - 1));
    }
    __syncthreads();

    // ---- last-block finalize: drain slots via atomicExch (coherent RMW,
    //      returns sum AND resets slot to 0 for the next call). ----
    if (is_last) {
        int i = threadIdx.x;
        float v = (i < TEXT_SLOTS + 48) ? atomicExch(&g_slot[i], 0.0f) : 0.0f;
        float vt = (i < TEXT_SLOTS) ? v : 0.0f;
        float v1 = (i >= SL_L1 && i < SL_L1 + 16) ? v : 0.0f;
        float v2 = (i >= SL_CL && i < SL_CL + 16) ? v : 0.0f;
        float v3 = (i >= SL_VF && i < SL_VF + 16) ? v : 0.0f;
        float text_sum = block_reduce_sum(vt);
        float s1 = block_reduce_sum(v1);
        float s2 = block_reduce_sum(v2);
        float s3 = block_reduce_sum(v3);
        if (threadIdx.x == 0) {
            float text = text_sum * (LN2 / (float)(B * HWc));  // ln domain + mean
            float denom = fmaxf(s3, 1.0f);
            bool any = s3 > 0.0f;
            float box  = any ? s1 / denom : 0.0f;
            float conf = any ? (s2 * LN2) / denom : 0.0f;
            out[0] = text + box + conf;    // all weights 1.0
            out[1] = text;
            out[2] = box;
            out[3] = conf;
        }
    }
}

}  // namespace

extern "C" void kernel_launch(void* const* d_in, const int* in_sizes, int n_in,
                              void* d_out, int out_size, void* d_ws, size_t ws_size,
                              hipStream_t stream) {
    const float* text_pred = (const float*)d_in[0];   // (16,1,512,512) f32
    const float* text_tgt  = (const float*)d_in[1];   // (16,1,512,512) f32
    const float* conf_pred = (const float*)d_in[2];   // (16,1,512,512) f32
    const float* bbox_pred = (const float*)d_in[3];   // (16,4,512,512) f32
    const float* box_conf  = (const float*)d_in[4];   // (16,256) f32
    const int*   box_xyxy  = (const int*)d_in[5];     // (16,256,4) i32
    const int*   box_mask  = (const int*)d_in[6];     // (16,256) bool->nonzero

    float* out = (float*)d_out;                       // 4 floats

    fused_kernel<<<NBLK, NTHR, 0, stream>>>(
        (const float4*)text_pred, (const float4*)text_tgt,
        conf_pred, bbox_pred, box_conf, box_xyxy, box_mask, out);
}

// Round 7
// 34.287 us; speedup vs baseline: 1.1468x; 1.1468x over previous
//
#include <hip/hip_runtime.h>

namespace {

constexpr int B = 16, H = 512, W = 512, N = 256;
constexpr int HWc = H * W;              // 262144
constexpr int NBLK = 2048;              // grid size (power of 2 for arrival mask)
constexpr int NTHR = 256;
constexpr int TEXT_SLOTS = 32;
constexpr int NSLOT = TEXT_SLOTS + 3 * 16;   // 80 logical slots
constexpr int SSTRIDE = 32;             // 32 floats = 128 B: one cache line per slot
// log2-domain clamp: max(ln(p), -100) == ln2 * max(log2(p), -100/ln2)
constexpr float LOG2_CLAMP = -144.26950408889634f;
constexpr float LN2 = 0.69314718055994531f;

// Cross-block state in module __device__ globals: zero-initialized at module
// load (harness poisons d_ws/d_out, never module globals). Invariant: every
// call leaves slots at zero (finalize drains with atomicExch(slot,0)).
// ALL cross-block communication is relaxed device-scope atomic RMWs executing
// at the LLC coherent point — no __threadfence anywhere (round-6 lesson: 1024
// per-block threadfences cost ~30+ µs of L2 cache-maintenance serialization;
// round-5 lesson: plain/relaxed cross-XCD *loads* see stale per-XCD L2).
__device__ float    g_slot[NSLOT * SSTRIDE];
__device__ unsigned g_cnt;              // monotonic arrival counter (never reset)

constexpr int SL_L1 = TEXT_SLOTS, SL_CL = TEXT_SLOTS + 16, SL_VF = TEXT_SLOTS + 32;

// BCE in log2 domain (== bce/ln2). Native v_log_f32; log2(0) = -inf -> clamped.
__device__ __forceinline__ float bce2(float p, float t) {
    float m1 = fmaxf(__log2f(p), LOG2_CLAMP);
    float m2 = fmaxf(__log2f(1.0f - p), LOG2_CLAMP);
    return fmaf(t, m2 - m1, -m2);          // -(t*m1 + (1-t)*m2)
}

__device__ __forceinline__ float smooth_l1(float pred, float tgt) {
    float d = fabsf(pred - tgt);
    return d < 1.0f ? 0.5f * d * d : d - 0.5f;
}

// Full-block (256-thread) sum; result valid on thread 0. Reusable (guarded).
__device__ __forceinline__ float block_reduce_sum(float v) {
    __shared__ float smem[4];
    for (int off = 32; off > 0; off >>= 1)
        v += __shfl_down(v, off, 64);
    int lane = threadIdx.x & 63, wid = threadIdx.x >> 6;
    __syncthreads();                       // guard smem reuse across calls
    if (lane == 0) smem[wid] = v;
    __syncthreads();
    if (threadIdx.x == 0) v = smem[0] + smem[1] + smem[2] + smem[3];
    return v;
}

// Single fused kernel: text BCE + box losses + last-block finalize.
__global__ __launch_bounds__(NTHR) void fused_kernel(
        const float4* __restrict__ p4,
        const float4* __restrict__ t4,
        const float*  __restrict__ conf_pred,
        const float*  __restrict__ bbox_pred,
        const float*  __restrict__ box_conf,
        const int*    __restrict__ box_xyxy,
        const int*    __restrict__ box_mask,
        float* __restrict__ out) {
    // ---- text-map BCE: 1,048,576 float4s, exactly 2 per thread ----
    int idx = blockIdx.x * NTHR + threadIdx.x;
    float acc = 0.0f;
    #pragma unroll
    for (int it = 0; it < 2; ++it) {
        int i = idx + it * (NBLK * NTHR);
        float4 p = p4[i];
        float4 t = t4[i];
        acc += bce2(p.x, t.x) + bce2(p.y, t.y) + bce2(p.z, t.z) + bce2(p.w, t.w);
    }
    float s = block_reduce_sum(acc);
    if (threadIdx.x == 0)
        atomicAdd(&g_slot[(blockIdx.x & (TEXT_SLOTS - 1)) * SSTRIDE], s);

    // ---- blocks 0..15: one batch of 256 boxes each (thread n = box n) ----
    if (blockIdx.x < B) {
        int b = blockIdx.x, n = threadIdx.x;
        int bi = b * N + n;
        int4 xy = reinterpret_cast<const int4*>(box_xyxy)[bi];  // x1,y1,x2,y2 in [0,512)
        int cx = (xy.x + xy.z) >> 1;       // nonneg -> >>1 == floor div 2
        int cy = (xy.y + xy.w) >> 1;
        bool valid = (box_mask[bi] != 0) && cx >= 0 && cx < W && cy >= 0 && cy < H;
        int cxc = min(max(cx, 0), W - 1);
        int cyc = min(max(cy, 0), H - 1);

        int base = ((b * 4) * H + cyc) * W + cxc;   // bbox_pred[b, 0, cy, cx]
        float l1 = 0.25f * (smooth_l1(bbox_pred[base          ], (float)xy.x * (1.0f / W)) +
                            smooth_l1(bbox_pred[base +     HWc], (float)xy.y * (1.0f / H)) +
                            smooth_l1(bbox_pred[base + 2 * HWc], (float)xy.z * (1.0f / W)) +
                            smooth_l1(bbox_pred[base + 3 * HWc], (float)xy.w * (1.0f / H)));
        float cl = bce2(conf_pred[(b * H + cyc) * W + cxc], box_conf[bi]);  // log2 dom

        float vf = valid ? 1.0f : 0.0f;
        float s1 = block_reduce_sum(l1 * vf);
        float s2 = block_reduce_sum(cl * vf);
        float s3 = block_reduce_sum(vf);
        if (threadIdx.x == 0) {
            atomicAdd(&g_slot[(SL_L1 + b) * SSTRIDE], s1);
            atomicAdd(&g_slot[(SL_CL + b) * SSTRIDE], s2);  // log2 dom; ×ln2 at end
            atomicAdd(&g_slot[(SL_VF + b) * SSTRIDE], s3);
        }
    }

    // ---- arrival: wait for this thread's slot-RMWs to complete at the LLC
    //      (bare vmcnt wait — NO cache maintenance), then count arrival.
    //      olds are K..K+2047, so the residue-2047 arrival is unique/call. ----
    __shared__ bool is_last;
    if (threadIdx.x == 0) {
        asm volatile("s_waitcnt vmcnt(0)" ::: "memory");
        unsigned old = atomicAdd(&g_cnt, 1u);
        is_last = ((old & (unsigned)(NBLK - 1)) == (unsigned)(NBLK - 1));
    }
    __syncthreads();

    // ---- last block: drain slots via atomicExch (LLC RMW — reads the
    //      up-to-date sum AND resets the slot to 0 for the next call). ----
    if (is_last) {
        int i = threadIdx.x;
        float v = (i < NSLOT) ? atomicExch(&g_slot[i * SSTRIDE], 0.0f) : 0.0f;
        float vt = (i < TEXT_SLOTS) ? v : 0.0f;
        float v1 = (i >= SL_L1 && i < SL_L1 + 16) ? v : 0.0f;
        float v2 = (i >= SL_CL && i < SL_CL + 16) ? v : 0.0f;
        float v3 = (i >= SL_VF && i < SL_VF + 16) ? v : 0.0f;
        float text_sum = block_reduce_sum(vt);
        float s1 = block_reduce_sum(v1);
        float s2 = block_reduce_sum(v2);
        float s3 = block_reduce_sum(v3);
        if (threadIdx.x == 0) {
            float text = text_sum * (LN2 / (float)(B * HWc));  // ln domain + mean
            float denom = fmaxf(s3, 1.0f);
            bool any = s3 > 0.0f;
            float box  = any ? s1 / denom : 0.0f;
            float conf = any ? (s2 * LN2) / denom : 0.0f;
            out[0] = text + box + conf;    // all weights 1.0
            out[1] = text;
            out[2] = box;
            out[3] = conf;
        }
    }
}

}  // namespace

extern "C" void kernel_launch(void* const* d_in, const int* in_sizes, int n_in,
                              void* d_out, int out_size, void* d_ws, size_t ws_size,
                              hipStream_t stream) {
    const float* text_pred = (const float*)d_in[0];   // (16,1,512,512) f32
    const float* text_tgt  = (const float*)d_in[1];   // (16,1,512,512) f32
    const float* conf_pred = (const float*)d_in[2];   // (16,1,512,512) f32
    const float* bbox_pred = (const float*)d_in[3];   // (16,4,512,512) f32
    const float* box_conf  = (const float*)d_in[4];   // (16,256) f32
    const int*   box_xyxy  = (const int*)d_in[5];     // (16,256,4) i32
    const int*   box_mask  = (const int*)d_in[6];     // (16,256) bool->nonzero

    float* out = (float*)d_out;                       // 4 floats

    fused_kernel<<<NBLK, NTHR, 0, stream>>>(
        (const float4*)text_pred, (const float4*)text_tgt,
        conf_pred, bbox_pred, box_conf, box_xyxy, box_mask, out);
}

// Round 8
// 13.998 us; speedup vs baseline: 2.8091x; 2.4495x over previous
//
#include <hip/hip_runtime.h>

namespace {

constexpr int B = 16, H = 512, W = 512, N = 256;
constexpr int HWc = H * W;              // 262144
constexpr int NBLK = 2048;
constexpr int NTHR = 256;
constexpr int TEXT_SLOTS = 32;
constexpr int NSLOT = TEXT_SLOTS + 3 * 16;   // 80 logical slots
constexpr int SSTRIDE = 32;             // 32 floats = 128 B: one line per slot
constexpr int L1CNT = 32;               // level-1 arrival counters
// log2-domain clamp: max(ln(p), -100) == ln2 * max(log2(p), -100/ln2)
constexpr float LOG2_CLAMP = -144.26950408889634f;
constexpr float LN2 = 0.69314718055994531f;

// HW lesson (rounds 1/6/7): same-LINE LLC atomics serialize at ~10-15 ns each.
// 2048 adds to one line = ~30 us. Keep every atomic line's depth <= 64:
//  - partial-sum slots: 128 B apart, 64 adds each (parallel across lines)
//  - arrival: two-level counter tree (64 adds/line, then 32 adds on one line)
// All cross-block communication is atomic RMW at the LLC coherent point —
// no plain loads of mutated data (round-5: stale per-XCD L2), no
// __threadfence (round-6: cache-maintenance cost).
// Module globals: zero at load; invariant: slots drained to 0 every call
// (atomicExch), counters monotonic with exact per-call quanta (residue test).
__device__ float    g_slot[NSLOT * SSTRIDE];
__device__ unsigned g_l1[L1CNT * SSTRIDE];   // 64 adds per counter per call
__device__ unsigned g_l2;                    // 32 adds per call

constexpr int SL_L1 = TEXT_SLOTS, SL_CL = TEXT_SLOTS + 16, SL_VF = TEXT_SLOTS + 32;

// BCE in log2 domain (== bce/ln2). Native v_log_f32; log2(0) = -inf -> clamped.
__device__ __forceinline__ float bce2(float p, float t) {
    float m1 = fmaxf(__log2f(p), LOG2_CLAMP);
    float m2 = fmaxf(__log2f(1.0f - p), LOG2_CLAMP);
    return fmaf(t, m2 - m1, -m2);          // -(t*m1 + (1-t)*m2)
}

__device__ __forceinline__ float smooth_l1(float pred, float tgt) {
    float d = fabsf(pred - tgt);
    return d < 1.0f ? 0.5f * d * d : d - 0.5f;
}

// Full-block (256-thread) sum; result valid on thread 0. Reusable (guarded).
__device__ __forceinline__ float block_reduce_sum(float v) {
    __shared__ float smem[4];
    for (int off = 32; off > 0; off >>= 1)
        v += __shfl_down(v, off, 64);
    int lane = threadIdx.x & 63, wid = threadIdx.x >> 6;
    __syncthreads();                       // guard smem reuse across calls
    if (lane == 0) smem[wid] = v;
    __syncthreads();
    if (threadIdx.x == 0) v = smem[0] + smem[1] + smem[2] + smem[3];
    return v;
}

// Single fused kernel: text BCE + box losses + last-block finalize.
__global__ __launch_bounds__(NTHR) void fused_kernel(
        const float4* __restrict__ p4,
        const float4* __restrict__ t4,
        const float*  __restrict__ conf_pred,
        const float*  __restrict__ bbox_pred,
        const float*  __restrict__ box_conf,
        const int*    __restrict__ box_xyxy,
        const int*    __restrict__ box_mask,
        float* __restrict__ out) {
    // ---- text-map BCE: 1,048,576 float4s, exactly 2 per thread ----
    int idx = blockIdx.x * NTHR + threadIdx.x;
    float acc = 0.0f;
    #pragma unroll
    for (int it = 0; it < 2; ++it) {
        int i = idx + it * (NBLK * NTHR);
        float4 p = p4[i];
        float4 t = t4[i];
        acc += bce2(p.x, t.x) + bce2(p.y, t.y) + bce2(p.z, t.z) + bce2(p.w, t.w);
    }
    float s = block_reduce_sum(acc);
    if (threadIdx.x == 0)
        atomicAdd(&g_slot[(blockIdx.x & (TEXT_SLOTS - 1)) * SSTRIDE], s);

    // ---- blocks 0..15: one batch of 256 boxes each (thread n = box n) ----
    if (blockIdx.x < B) {
        int b = blockIdx.x, n = threadIdx.x;
        int bi = b * N + n;
        int4 xy = reinterpret_cast<const int4*>(box_xyxy)[bi];  // x1,y1,x2,y2 in [0,512)
        int cx = (xy.x + xy.z) >> 1;       // nonneg -> >>1 == floor div 2
        int cy = (xy.y + xy.w) >> 1;
        bool valid = (box_mask[bi] != 0) && cx >= 0 && cx < W && cy >= 0 && cy < H;
        int cxc = min(max(cx, 0), W - 1);
        int cyc = min(max(cy, 0), H - 1);

        int base = ((b * 4) * H + cyc) * W + cxc;   // bbox_pred[b, 0, cy, cx]
        float l1 = 0.25f * (smooth_l1(bbox_pred[base          ], (float)xy.x * (1.0f / W)) +
                            smooth_l1(bbox_pred[base +     HWc], (float)xy.y * (1.0f / H)) +
                            smooth_l1(bbox_pred[base + 2 * HWc], (float)xy.z * (1.0f / W)) +
                            smooth_l1(bbox_pred[base + 3 * HWc], (float)xy.w * (1.0f / H)));
        float cl = bce2(conf_pred[(b * H + cyc) * W + cxc], box_conf[bi]);  // log2 dom

        float vf = valid ? 1.0f : 0.0f;
        float s1 = block_reduce_sum(l1 * vf);
        float s2 = block_reduce_sum(cl * vf);
        float s3 = block_reduce_sum(vf);
        if (threadIdx.x == 0) {
            atomicAdd(&g_slot[(SL_L1 + b) * SSTRIDE], s1);
            atomicAdd(&g_slot[(SL_CL + b) * SSTRIDE], s2);  // log2 dom; ×ln2 at end
            atomicAdd(&g_slot[(SL_VF + b) * SSTRIDE], s3);
        }
    }

    // ---- arrival: two-level tree, every line <= 64 deep. Monotonic counters;
    //      exact per-call quanta (64 per L1 counter, 32 at L2) make the
    //      residue test fire exactly once per call for any start value. ----
    __shared__ bool is_last;
    if (threadIdx.x == 0) {
        asm volatile("s_waitcnt vmcnt(0)" ::: "memory");   // slot RMWs ack'd at LLC
        unsigned o1 = atomicAdd(&g_l1[(blockIdx.x & (L1CNT - 1)) * SSTRIDE], 1u);
        bool l2_last = false;
        if ((o1 & 63u) == 63u) {                           // 64th arrival on this counter
            unsigned o2 = atomicAdd(&g_l2, 1u);
            l2_last = ((o2 & (unsigned)(L1CNT - 1)) == (unsigned)(L1CNT - 1));
        }
        is_last = l2_last;
    }
    __syncthreads();

    // ---- last block: drain slots via atomicExch (coherent RMW — reads the
    //      final sum AND resets the slot to 0 for the next call). ----
    if (is_last) {
        int i = threadIdx.x;
        float v = (i < NSLOT) ? atomicExch(&g_slot[i * SSTRIDE], 0.0f) : 0.0f;
        float vt = (i < TEXT_SLOTS) ? v : 0.0f;
        float v1 = (i >= SL_L1 && i < SL_L1 + 16) ? v : 0.0f;
        float v2 = (i >= SL_CL && i < SL_CL + 16) ? v : 0.0f;
        float v3 = (i >= SL_VF && i < SL_VF + 16) ? v : 0.0f;
        float text_sum = block_reduce_sum(vt);
        float s1 = block_reduce_sum(v1);
        float s2 = block_reduce_sum(v2);
        float s3 = block_reduce_sum(v3);
        if (threadIdx.x == 0) {
            float text = text_sum * (LN2 / (float)(B * HWc));  // ln domain + mean
            float denom = fmaxf(s3, 1.0f);
            bool any = s3 > 0.0f;
            float box  = any ? s1 / denom : 0.0f;
            float conf = any ? (s2 * LN2) / denom : 0.0f;
            out[0] = text + box + conf;    // all weights 1.0
            out[1] = text;
            out[2] = box;
            out[3] = conf;
        }
    }
}

}  // namespace

extern "C" void kernel_launch(void* const* d_in, const int* in_sizes, int n_in,
                              void* d_out, int out_size, void* d_ws, size_t ws_size,
                              hipStream_t stream) {
    const float* text_pred = (const float*)d_in[0];   // (16,1,512,512) f32
    const float* text_tgt  = (const float*)d_in[1];   // (16,1,512,512) f32
    const float* conf_pred = (const float*)d_in[2];   // (16,1,512,512) f32
    const float* bbox_pred = (const float*)d_in[3];   // (16,4,512,512) f32
    const float* box_conf  = (const float*)d_in[4];   // (16,256) f32
    const int*   box_xyxy  = (const int*)d_in[5];     // (16,256,4) i32
    const int*   box_mask  = (const int*)d_in[6];     // (16,256) bool->nonzero

    float* out = (float*)d_out;                       // 4 floats

    fused_kernel<<<NBLK, NTHR, 0, stream>>>(
        (const float4*)text_pred, (const float4*)text_tgt,
        conf_pred, bbox_pred, box_conf, box_xyxy, box_mask, out);
}